// Round 3
// baseline (358.114 us; speedup 1.0000x reference)
//
#include <hip/hip_runtime.h>
#include <hip/hip_bf16.h>
#include <math.h>

#define NN 100000
#define NE 1600000
#define FF 128
#define HH 64
#define CC 10
#define GG 128
#define BN_EPS 1e-5f

// bucketed-edge constants
#define BNODES 64               // nodes per bucket (dst>>6)
#define NB 1563                 // ceil(NN/BNODES)
#define PBLK 128                // partition blocks (counting sort)
#define ECHUNK 12500            // NE / PBLK exactly
#define MHIST (NB * PBLK)       // 200064
#define NSCAN 782               // ceil(MHIST/256)
#define SCOL_CAP 2048           // max edges/bucket in LDS (mean 1024, +32 sigma)

typedef short v8bf __attribute__((ext_vector_type(8)));
typedef float v4f  __attribute__((ext_vector_type(4)));

__device__ inline ushort f2b(float x) {
    __hip_bfloat16 h = __float2bfloat16(x);
    return *reinterpret_cast<ushort*>(&h);
}
__device__ inline float b2f(ushort u) {
    return __uint_as_float(((unsigned)u) << 16);
}
__device__ inline float blo(unsigned u) { return __uint_as_float(u << 16); }
__device__ inline float bhi(unsigned u) { return __uint_as_float(u & 0xffff0000u); }

// accumulate one 128-bit chunk (8 bf16 channels) into a[8]
__device__ inline void acc8(float* a, const uint4 r) {
    a[0] += blo(r.x); a[1] += bhi(r.x); a[2] += blo(r.y); a[3] += bhi(r.y);
    a[4] += blo(r.z); a[5] += bhi(r.z); a[6] += blo(r.w); a[7] += bhi(r.w);
}

// ---------------- weight swizzle helper (runs inside edge_hist extra blocks) -------
__device__ inline void sw_one(const float* __restrict__ W, ushort* __restrict__ o,
                              int t, int K) {
    const int lane = t & 63, nt = (t >> 6) & 3, ks = t >> 8;
    const int m = lane & 15, quad = lane >> 4;
#pragma unroll
    for (int j = 0; j < 8; ++j) {
        const int kk = ks * 32 + quad * 8 + j;
        const int cc = nt * 16 + m;
        o[t * 8 + j] = f2b(W[kk * 64 + cc]);
    }
}

// ---------------- dual MFMA GEMM: Yl = X@Wl, Yr = X@Wr (bf16 out) ----------------
template<int K, int TPB, bool AF32>
__global__ __launch_bounds__(256) void gemm_mfma(const void* __restrict__ Xv,
                                                 const ushort* __restrict__ Bl,
                                                 const ushort* __restrict__ Br,
                                                 ushort* __restrict__ Yl,
                                                 ushort* __restrict__ Yr) {
    constexpr int KS = K / 32;
    const int lane  = threadIdx.x & 63;
    const int wave  = threadIdx.x >> 6;
    const int nhalf = wave & 1;
    const int rsub  = wave >> 1;
    const int m = lane & 15, quad = lane >> 4;

    v8bf bl[KS][2], br[KS][2];
#pragma unroll
    for (int ks = 0; ks < KS; ++ks)
#pragma unroll
        for (int nt = 0; nt < 2; ++nt) {
            const int nti = nhalf * 2 + nt;
            bl[ks][nt] = *(const v8bf*)(Bl + ((size_t)(ks * 4 + nti) * 64 + lane) * 8);
            br[ks][nt] = *(const v8bf*)(Br + ((size_t)(ks * 4 + nti) * 64 + lane) * 8);
        }

    for (int it = 0; it < TPB; ++it) {
        const int bt = blockIdx.x * TPB + it;
        const int row0 = bt * 32 + rsub * 16;
        if (row0 >= NN) return;
        const v4f z = {0.f, 0.f, 0.f, 0.f};
        v4f accl[2] = {z, z}, accr[2] = {z, z};
#pragma unroll
        for (int ks = 0; ks < KS; ++ks) {
            v8bf a;
            if (AF32) {
                const float* xrow = (const float*)Xv + (size_t)(row0 + m) * K + quad * 8 + ks * 32;
                const float4 a0 = *(const float4*)(xrow);
                const float4 a1 = *(const float4*)(xrow + 4);
                a[0] = (short)f2b(a0.x); a[1] = (short)f2b(a0.y);
                a[2] = (short)f2b(a0.z); a[3] = (short)f2b(a0.w);
                a[4] = (short)f2b(a1.x); a[5] = (short)f2b(a1.y);
                a[6] = (short)f2b(a1.z); a[7] = (short)f2b(a1.w);
            } else {
                const ushort* xrow = (const ushort*)Xv + (size_t)(row0 + m) * K + quad * 8 + ks * 32;
                a = *(const v8bf*)xrow;
            }
#pragma unroll
            for (int nt = 0; nt < 2; ++nt) {
                accl[nt] = __builtin_amdgcn_mfma_f32_16x16x32_bf16(a, bl[ks][nt], accl[nt], 0, 0, 0);
                accr[nt] = __builtin_amdgcn_mfma_f32_16x16x32_bf16(a, br[ks][nt], accr[nt], 0, 0, 0);
            }
        }
#pragma unroll
        for (int nt = 0; nt < 2; ++nt) {
            const int cc = nhalf * 32 + nt * 16 + m;
#pragma unroll
            for (int r = 0; r < 4; ++r) {
                const size_t off = (size_t)(row0 + quad * 4 + r) * 64 + cc;
                Yl[off] = f2b(accl[nt][r]);
                Yr[off] = f2b(accr[nt][r]);
            }
        }
    }
}

// ---------------- pass A1: per-(block,bucket) histogram + fused prep ----------------
__global__ __launch_bounds__(1024) void edge_hist(const int* __restrict__ dst,
                                                  int* __restrict__ hist,
                                                  const float* __restrict__ W1l,
                                                  const float* __restrict__ W1r,
                                                  const float* __restrict__ W2l,
                                                  const float* __restrict__ W2r,
                                                  ushort* __restrict__ w1ls,
                                                  ushort* __restrict__ w1rs,
                                                  ushort* __restrict__ w2ls,
                                                  ushort* __restrict__ w2rs,
                                                  float* __restrict__ gz) {
    if (blockIdx.x >= PBLK) {
        const int t = threadIdx.x;
        if (blockIdx.x == PBLK) {              // 1024 threads: K=128 swizzles
            sw_one(W1l, w1ls, t, FF);
            sw_one(W1r, w1rs, t, FF);
        } else {
            if (t < 512) {                     // K=64 swizzles
                sw_one(W2l, w2ls, t, HH);
                sw_one(W2r, w2rs, t, HH);
            } else {                           // zero gsum (GG*64) + gcnt (GG)
                for (int i = t - 512; i < GG * 64 + GG; i += 512) gz[i] = 0.f;
            }
        }
        return;
    }
    __shared__ int h[NB];
    for (int i = threadIdx.x; i < NB; i += 1024) h[i] = 0;
    __syncthreads();
    const int e0 = blockIdx.x * ECHUNK;
    for (int e = e0 + threadIdx.x; e < e0 + ECHUNK; e += 1024)
        atomicAdd(&h[dst[e] >> 6], 1);
    __syncthreads();
    for (int i = threadIdx.x; i < NB; i += 1024)
        hist[i * PBLK + blockIdx.x] = h[i];   // bucket-major for the scan
}

// ---------------- pass A2: scan (wave-shuffle scan; boff folded into consumers) -----
__global__ __launch_bounds__(256) void scan_block(const int* __restrict__ cnt,
                                                  int* __restrict__ rp,
                                                  int* __restrict__ bsum) {
    __shared__ int ws[4];
    const int tid = threadIdx.x;
    const int lane = tid & 63, wv = tid >> 6;
    const int i = blockIdx.x * 256 + tid;
    const int v = (i < MHIST) ? cnt[i] : 0;
    int inc = v;
#pragma unroll
    for (int off = 1; off < 64; off <<= 1) {
        int t = __shfl_up(inc, off, 64);
        if (lane >= off) inc += t;
    }
    if (lane == 63) ws[wv] = inc;
    __syncthreads();
    int wbase = 0;
#pragma unroll
    for (int w = 0; w < 4; ++w) wbase += (w < wv) ? ws[w] : 0;
    if (i < MHIST) rp[i] = wbase + inc - v;           // exclusive prefix
    if (tid == 255) bsum[blockIdx.x] = wbase + inc;   // block total
}

// scan of NSCAN block sums: 256 threads x 4 elements each (wave-shuffle scan)
__global__ __launch_bounds__(256) void scan_bsums(const int* __restrict__ bsum,
                                                  int* __restrict__ boff) {
    __shared__ int ws[4];
    const int tid = threadIdx.x;
    const int lane = tid & 63, wv = tid >> 6;
    int v[4];
    int tot = 0;
#pragma unroll
    for (int j = 0; j < 4; ++j) {
        const int idx = tid * 4 + j;
        v[j] = (idx < NSCAN) ? bsum[idx] : 0;
        tot += v[j];
    }
    int inc = tot;
#pragma unroll
    for (int off = 1; off < 64; off <<= 1) {
        int t = __shfl_up(inc, off, 64);
        if (lane >= off) inc += t;
    }
    if (lane == 63) ws[wv] = inc;
    __syncthreads();
    int wbase = 0;
#pragma unroll
    for (int w = 0; w < 4; ++w) wbase += (w < wv) ? ws[w] : 0;
    int run = wbase + inc - tot;   // exclusive base for this thread's 4
#pragma unroll
    for (int j = 0; j < 4; ++j) {
        const int idx = tid * 4 + j;
        if (idx < NSCAN) boff[idx] = run;
        run += v[j];
    }
}

// ---------------- pass A3: LDS counting-sort + near-contiguous scatter ----------
__global__ __launch_bounds__(1024) void edge_scatter(const int* __restrict__ src,
                                                     const int* __restrict__ dst,
                                                     const int* __restrict__ hist,
                                                     const int* __restrict__ goffs,
                                                     const int* __restrict__ boff,
                                                     int* __restrict__ pairs) {
    __shared__ int sv[ECHUNK];      // 50000 B: packed (src<<6)|dstLocal, bucket-sorted
    __shared__ int sd[ECHUNK];      // 50000 B: global destination index
    __shared__ int sfill[NB];       //  6252 B: local fill cursor per bucket
    __shared__ int sdelta[NB];      //  6252 B: global_base - local_start per bucket
    __shared__ int wsum[16];
    const int tid = threadIdx.x;
    const int lane = tid & 63, wv = tid >> 6;
    const int p = blockIdx.x;

    int c0 = 0, c1 = 0, g0 = 0, g1 = 0;
    const int i0 = 2 * tid, i1 = 2 * tid + 1;
    if (i0 < NB) {
        const int idx = i0 * PBLK + p;
        c0 = hist[idx];
        g0 = goffs[idx] + boff[idx >> 8];
    }
    if (i1 < NB) {
        const int idx = i1 * PBLK + p;
        c1 = hist[idx];
        g1 = goffs[idx] + boff[idx >> 8];
    }
    const int tv = c0 + c1;
    int inc = tv;
#pragma unroll
    for (int off = 1; off < 64; off <<= 1) {
        int t = __shfl_up(inc, off, 64);
        if (lane >= off) inc += t;
    }
    if (lane == 63) wsum[wv] = inc;
    __syncthreads();
    int wbase = 0;
#pragma unroll
    for (int w = 0; w < 16; ++w) wbase += (w < wv) ? wsum[w] : 0;
    const int excl = wbase + inc - tv;   // local_start for bucket i0
    if (i0 < NB) { sfill[i0] = excl;      sdelta[i0] = g0 - excl; }
    if (i1 < NB) { sfill[i1] = excl + c0; sdelta[i1] = g1 - (excl + c0); }
    __syncthreads();

    const int e0 = p * ECHUNK;
    for (int e = e0 + tid; e < e0 + ECHUNK; e += 1024) {
        const int s = src[e];
        const int d = dst[e];
        const int b = d >> 6;
        const int local = atomicAdd(&sfill[b], 1);
        sv[local] = (s << 6) | (d & (BNODES - 1));
        sd[local] = local + sdelta[b];
    }
    __syncthreads();

    for (int j = tid; j < ECHUNK; j += 1024) {
        pairs[sd[j]] = sv[j];
    }
}

// ---------------- pass B: balanced edge-chunk gather + LDS accum + fused epilogue ----
// Phase 4 assigns each 8-lane group an equal contiguous chunk of the bucket's
// dst-sorted edge array (zero degree-divergence, perfect balance). Runs of equal
// dst accumulate in registers; run boundaries flush 8 LDS atomicAdds into
// accum[64][65] (stride 65 -> bank spread). Epilogue reads accum.
template<bool POOL>
__global__ __launch_bounds__(256) void spmm_sorted(const int* __restrict__ goffs,
                                                   const int* __restrict__ boff,
                                                   const int* __restrict__ pairs,
                                                   const ushort* __restrict__ Yl,
                                                   const ushort* __restrict__ Yr,
                                                   const float* __restrict__ bias,
                                                   const float* __restrict__ bng,
                                                   const float* __restrict__ bnb,
                                                   const float* __restrict__ bnm,
                                                   const float* __restrict__ bnv,
                                                   ushort* __restrict__ outp,
                                                   const int* __restrict__ batch,
                                                   float* __restrict__ gsum,
                                                   float* __restrict__ gcnt) {
    __shared__ int scol[SCOL_CAP];      // 8 KB: dst-sorted packed (src<<6)|dl
    __shared__ float accum[BNODES][65]; // 16.6 KB: per-node channel sums
    __shared__ int deg[BNODES];
    __shared__ int loffs[BNODES];       // inclusive scan of deg
    __shared__ int fill[BNODES];
    __shared__ float pbuf[4][64];       // pool partials (POOL only)
    __shared__ float pcnt[4];
    __shared__ int g0s;
    const int tid = threadIdx.x;
    const int b = blockIdx.x;

    if (tid < BNODES) { deg[tid] = 0; fill[tid] = 0; }
    for (int i = tid; i < BNODES * 65; i += 256) (&accum[0][0])[i] = 0.f;
    if (POOL) {
        pbuf[tid >> 6][tid & 63] = 0.f;
        if (tid < 4) pcnt[tid] = 0.f;
        if (tid == 0) g0s = batch[b * BNODES];
    }
    __syncthreads();

    const int beg = goffs[b * PBLK] + boff[b >> 1];
    int end = (b == NB - 1) ? NE : goffs[(b + 1) * PBLK] + boff[(b + 1) >> 1];
    if (end - beg > SCOL_CAP) end = beg + SCOL_CAP;

    // phase 1: per-dstLocal degree count (cache pairs in registers for phase 3)
    int pv[8];
    int npv = 0;
    for (int i = beg + tid; i < end; i += 256) {
        const int v = pairs[i];
        pv[npv++] = v;
        atomicAdd(&deg[v & (BNODES - 1)], 1);
    }
    __syncthreads();

    // phase 2: inclusive scan of deg -> loffs (wave 0 shuffle scan)
    if (tid < BNODES) {
        const int v = deg[tid];
        int inc = v;
#pragma unroll
        for (int s = 1; s < 64; s <<= 1) {
            int t = __shfl_up(inc, s, 64);
            if (tid >= s) inc += t;
        }
        loffs[tid] = inc;
    }
    __syncthreads();

    // phase 3: scatter packed values into dst-sorted order (from register cache)
    for (int j = 0; j < npv; ++j) {
        const int v = pv[j];
        const int dl = v & (BNODES - 1);
        const int pos = (loffs[dl] - deg[dl]) + atomicAdd(&fill[dl], 1);
        scol[pos] = v;
    }
    __syncthreads();

    // phase 4: balanced chunked gather. 32 groups of 8 lanes; group gid takes
    // edges [gid*chunk, (gid+1)*chunk). chunk forced odd -> scol bank spread.
    const int gid = tid >> 3, subl = tid & 7;
    const int nedges = end - beg;
    const int chunk = ((nedges + 31) >> 5) | 1;
    int e = gid * chunk;
    const int gend = (e + chunk < nedges) ? e + chunk : nedges;
    float racc[8] = {0.f, 0.f, 0.f, 0.f, 0.f, 0.f, 0.f, 0.f};
    int cur = -1;

    int v0 = 0, v1 = 0, v2 = 0, v3 = 0;
    if (e + 3 < gend) { v0 = scol[e]; v1 = scol[e + 1]; v2 = scol[e + 2]; v3 = scol[e + 3]; }
    while (e + 3 < gend) {
        const uint4 r0 = *(const uint4*)(Yl + (size_t)(v0 >> 6) * 64 + subl * 8);
        const uint4 r1 = *(const uint4*)(Yl + (size_t)(v1 >> 6) * 64 + subl * 8);
        const uint4 r2 = *(const uint4*)(Yl + (size_t)(v2 >> 6) * 64 + subl * 8);
        const uint4 r3 = *(const uint4*)(Yl + (size_t)(v3 >> 6) * 64 + subl * 8);
        const int d0 = v0 & 63, d1 = v1 & 63, d2 = v2 & 63, d3 = v3 & 63;
        const int en = e + 4;
        if (en + 3 < gend) {            // preload next batch's indices (hides ds latency)
            v0 = scol[en]; v1 = scol[en + 1]; v2 = scol[en + 2]; v3 = scol[en + 3];
        }
        if (d0 != cur) {
            if (cur >= 0) {
#pragma unroll
                for (int j = 0; j < 8; ++j) { atomicAdd(&accum[cur][subl * 8 + j], racc[j]); racc[j] = 0.f; }
            }
            cur = d0;
        }
        if (d0 == d3) {                 // common case: whole batch in one run
            acc8(racc, r0); acc8(racc, r1); acc8(racc, r2); acc8(racc, r3);
        } else {
            acc8(racc, r0);
            if (d1 != cur) {
#pragma unroll
                for (int j = 0; j < 8; ++j) { atomicAdd(&accum[cur][subl * 8 + j], racc[j]); racc[j] = 0.f; }
                cur = d1;
            }
            acc8(racc, r1);
            if (d2 != cur) {
#pragma unroll
                for (int j = 0; j < 8; ++j) { atomicAdd(&accum[cur][subl * 8 + j], racc[j]); racc[j] = 0.f; }
                cur = d2;
            }
            acc8(racc, r2);
            if (d3 != cur) {
#pragma unroll
                for (int j = 0; j < 8; ++j) { atomicAdd(&accum[cur][subl * 8 + j], racc[j]); racc[j] = 0.f; }
                cur = d3;
            }
            acc8(racc, r3);
        }
        e = en;
    }
    for (; e < gend; ++e) {             // remainder (<4 edges)
        const int v = scol[e];
        const uint4 r = *(const uint4*)(Yl + (size_t)(v >> 6) * 64 + subl * 8);
        const int d = v & 63;
        if (d != cur) {
            if (cur >= 0) {
#pragma unroll
                for (int j = 0; j < 8; ++j) { atomicAdd(&accum[cur][subl * 8 + j], racc[j]); racc[j] = 0.f; }
            }
            cur = d;
        }
        acc8(racc, r);
    }
    if (cur >= 0) {
#pragma unroll
        for (int j = 0; j < 8; ++j) { atomicAdd(&accum[cur][subl * 8 + j], racc[j]); racc[j] = 0.f; }
    }
    __syncthreads();

    // phase 5: epilogue — mean + bias + root + BN + ReLU (+ pool or store)
    const int wv = tid >> 6, lane = tid & 63;
    const int grp = lane >> 3;

    float biasj[8], scj[8], mj[8], bbj[8];
#pragma unroll
    for (int j = 0; j < 8; ++j) {
        const int ch = subl * 8 + j;
        biasj[j] = bias[ch];
        scj[j] = bng[ch] * rsqrtf(bnv[ch] + BN_EPS);
        mj[j] = bnm[ch];
        bbj[j] = bnb[ch];
    }

    for (int i = 0; i < 2; ++i) {
        const int nl = wv * 16 + i * 8 + grp;
        const int node = b * BNODES + nl;
        if (node >= NN) continue;
        const int dg = deg[nl];
        const float inv = 1.0f / fmaxf((float)dg, 1.0f);
        const uint4 yr = *(const uint4*)(Yr + (size_t)node * 64 + subl * 8);
        float hj[8];
        hj[0] = accum[nl][subl * 8 + 0] * inv + biasj[0] + blo(yr.x);
        hj[1] = accum[nl][subl * 8 + 1] * inv + biasj[1] + bhi(yr.x);
        hj[2] = accum[nl][subl * 8 + 2] * inv + biasj[2] + blo(yr.y);
        hj[3] = accum[nl][subl * 8 + 3] * inv + biasj[3] + bhi(yr.y);
        hj[4] = accum[nl][subl * 8 + 4] * inv + biasj[4] + blo(yr.z);
        hj[5] = accum[nl][subl * 8 + 5] * inv + biasj[5] + bhi(yr.z);
        hj[6] = accum[nl][subl * 8 + 6] * inv + biasj[6] + blo(yr.w);
        hj[7] = accum[nl][subl * 8 + 7] * inv + biasj[7] + bhi(yr.w);
        float o[8];
#pragma unroll
        for (int j = 0; j < 8; ++j)
            o[j] = fmaxf((hj[j] - mj[j]) * scj[j] + bbj[j], 0.0f);
        if (!POOL) {
            unsigned ow[4];
#pragma unroll
            for (int j = 0; j < 4; ++j)
                ow[j] = (unsigned)f2b(o[2 * j]) | ((unsigned)f2b(o[2 * j + 1]) << 16);
            uint4 ov;
            ov.x = ow[0]; ov.y = ow[1]; ov.z = ow[2]; ov.w = ow[3];
            *(uint4*)(outp + (size_t)node * 64 + subl * 8) = ov;
        } else {
            const int g = batch[node];
            const int gi = g - g0s;
            if (gi < 4) {
#pragma unroll
                for (int j = 0; j < 8; ++j) atomicAdd(&pbuf[gi][subl * 8 + j], o[j]);
                if (subl == 0) atomicAdd(&pcnt[gi], 1.0f);
            } else {   // span > 4 graphs in one block: direct (rare/never)
#pragma unroll
                for (int j = 0; j < 8; ++j) atomicAdd(&gsum[g * 64 + subl * 8 + j], o[j]);
                if (subl == 0) atomicAdd(&gcnt[g], 1.0f);
            }
        }
    }
    if (POOL) {
        __syncthreads();
        const int q = tid >> 6, ch = tid & 63;
        const int g = g0s + q;
        if (g < GG) {
            const float v = pbuf[q][ch];
            if (v != 0.f) atomicAdd(&gsum[g * 64 + ch], v);
        }
        if (tid < 4) {
            const int gq = g0s + tid;
            if (gq < GG && pcnt[tid] > 0.f) atomicAdd(&gcnt[gq], pcnt[tid]);
        }
    }
}

// ---------------- classifier head ----------------
__global__ __launch_bounds__(64) void head_kernel(const float* __restrict__ gsum,
                                                  const float* __restrict__ gcnt,
                                                  const float* __restrict__ Wc1,
                                                  const float* __restrict__ bc1,
                                                  const float* __restrict__ g3,
                                                  const float* __restrict__ b3,
                                                  const float* __restrict__ m3,
                                                  const float* __restrict__ v3,
                                                  const float* __restrict__ Wc2,
                                                  const float* __restrict__ bc2,
                                                  float* __restrict__ out) {
    __shared__ float sg[64];
    __shared__ float st[64];
    __shared__ float sl[10];
    __shared__ float sls;
    const int b = blockIdx.x;
    const int c = threadIdx.x;
    sg[c] = gsum[b * 64 + c] / fmaxf(gcnt[b], 1.0f);
    __syncthreads();
    float acc = bc1[c];
#pragma unroll
    for (int k = 0; k < 64; ++k) acc += sg[k] * Wc1[k * 64 + c];
    const float sc = g3[c] * rsqrtf(v3[c] + BN_EPS);
    st[c] = fmaxf((acc - m3[c]) * sc + b3[c], 0.0f);
    __syncthreads();
    if (c < CC) {
        float lg = bc2[c];
#pragma unroll
        for (int k = 0; k < 64; ++k) lg += st[k] * Wc2[k * CC + c];
        sl[c] = lg;
    }
    __syncthreads();
    if (c == 0) {
        float mx = sl[0];
        for (int i = 1; i < CC; ++i) mx = fmaxf(mx, sl[i]);
        float s = 0.f;
        for (int i = 0; i < CC; ++i) s += expf(sl[i] - mx);
        sls = mx + logf(s);
    }
    __syncthreads();
    if (c < CC) out[b * CC + c] = sl[c] - sls;
}

extern "C" void kernel_launch(void* const* d_in, const int* in_sizes, int n_in,
                              void* d_out, int out_size, void* d_ws, size_t ws_size,
                              hipStream_t stream) {
    const float* x    = (const float*)d_in[0];
    const int*   ei   = (const int*)d_in[1];
    const int*   batch= (const int*)d_in[2];
    const float* W1l  = (const float*)d_in[3];
    const float* W1r  = (const float*)d_in[4];
    const float* b1   = (const float*)d_in[5];
    const float* W2l  = (const float*)d_in[6];
    const float* W2r  = (const float*)d_in[7];
    const float* b2   = (const float*)d_in[8];
    const float* bn1g = (const float*)d_in[9];
    const float* bn1b = (const float*)d_in[10];
    const float* bn1m = (const float*)d_in[11];
    const float* bn1v = (const float*)d_in[12];
    const float* bn2g = (const float*)d_in[13];
    const float* bn2b = (const float*)d_in[14];
    const float* bn2m = (const float*)d_in[15];
    const float* bn2v = (const float*)d_in[16];
    const float* bn3g = (const float*)d_in[17];
    const float* bn3b = (const float*)d_in[18];
    const float* bn3m = (const float*)d_in[19];
    const float* bn3v = (const float*)d_in[20];
    const float* Wc1  = (const float*)d_in[21];
    const float* bc1  = (const float*)d_in[22];
    const float* Wc2  = (const float*)d_in[23];
    const float* bc2  = (const float*)d_in[24];
    float* out = (float*)d_out;

    const int* src = ei;
    const int* dst = ei + NE;

    // workspace layout (all blocks 16B-aligned)
    char* p = (char*)d_ws;
    ushort* yl   = (ushort*)p;                 p += (size_t)NN * 64 * 2;        // 12.8 MB
    ushort* yr   = (ushort*)p;                 p += (size_t)NN * 64 * 2;        // 12.8 MB
    ushort* hbuf = (ushort*)p;                 p += (size_t)NN * 64 * 2;        // 12.8 MB
    int*    pairs= (int*)p;                    p += (size_t)NE * 4;             // 6.4 MB
    int*    hist = (int*)p;                    p += (size_t)MHIST * 4;         // 800 KB
    int*    goffs= (int*)p;                    p += (size_t)MHIST * 4;         // 800 KB
    int*    bsum = (int*)p;                    p += 1024 * 4;
    int*    boff = (int*)p;                    p += 1024 * 4;
    ushort* w1ls = (ushort*)p;                 p += (size_t)FF * 64 * 2;
    ushort* w1rs = (ushort*)p;                 p += (size_t)FF * 64 * 2;
    ushort* w2ls = (ushort*)p;                 p += (size_t)HH * 64 * 2;
    ushort* w2rs = (ushort*)p;                 p += (size_t)HH * 64 * 2;
    float* gsum  = (float*)p;                  p += (size_t)GG * 64 * 4;        // gsum+gcnt
    float* gcnt  = gsum + GG * 64;             p += (size_t)GG * 4;             //  contiguous

    // ---- edge counting sort (once, reused by both layers) + fused prep ----
    edge_hist<<<PBLK + 2, 1024, 0, stream>>>(dst, hist, W1l, W1r, W2l, W2r,
                                             w1ls, w1rs, w2ls, w2rs, gsum);
    scan_block<<<NSCAN, 256, 0, stream>>>(hist, goffs, bsum);
    scan_bsums<<<1, 256, 0, stream>>>(bsum, boff);
    edge_scatter<<<PBLK, 1024, 0, stream>>>(src, dst, hist, goffs, boff, pairs);

    // ---- layer 1 ----
    gemm_mfma<FF, 2, true><<<1563, 256, 0, stream>>>((const void*)x, w1ls, w1rs, yl, yr);
    spmm_sorted<false><<<NB, 256, 0, stream>>>(goffs, boff, pairs, yl, yr, b1,
                                               bn1g, bn1b, bn1m, bn1v, hbuf,
                                               batch, gsum, gcnt);

    // ---- layer 2 (pool fused into spmm epilogue; no h write) ----
    gemm_mfma<HH, 2, false><<<1563, 256, 0, stream>>>((const void*)hbuf, w2ls, w2rs, yl, yr);
    spmm_sorted<true><<<NB, 256, 0, stream>>>(goffs, boff, pairs, yl, yr, b2,
                                              bn2g, bn2b, bn2m, bn2v, hbuf,
                                              batch, gsum, gcnt);

    // ---- head ----
    head_kernel<<<GG, 64, 0, stream>>>(gsum, gcnt, Wc1, bc1,
                                       bn3g, bn3b, bn3m, bn3v, Wc2, bc2, out);
}

// Round 4
// 349.893 us; speedup vs baseline: 1.0235x; 1.0235x over previous
//
#include <hip/hip_runtime.h>
#include <hip/hip_bf16.h>
#include <math.h>

#define NN 100000
#define NE 1600000
#define FF 128
#define HH 64
#define CC 10
#define GG 128
#define BN_EPS 1e-5f

// bucketed-edge constants
#define BNODES 64               // nodes per bucket (dst>>6)
#define NB 1563                 // ceil(NN/BNODES)
#define PBLK 128                // partition blocks (counting sort)
#define ECHUNK 12500            // NE / PBLK exactly
#define MHIST (NB * PBLK)       // 200064
#define NSCAN 782               // ceil(MHIST/256)
#define SCOL_CAP 2048           // max edges/bucket in LDS (mean 1024, +32 sigma)

typedef short v8bf __attribute__((ext_vector_type(8)));
typedef float v4f  __attribute__((ext_vector_type(4)));

__device__ inline ushort f2b(float x) {
    __hip_bfloat16 h = __float2bfloat16(x);
    return *reinterpret_cast<ushort*>(&h);
}
__device__ inline float b2f(ushort u) {
    return __uint_as_float(((unsigned)u) << 16);
}
__device__ inline float blo(unsigned u) { return __uint_as_float(u << 16); }
__device__ inline float bhi(unsigned u) { return __uint_as_float(u & 0xffff0000u); }

// accumulate one 128-bit chunk (8 bf16 channels) into a[8]
__device__ inline void acc8(float* a, const uint4 r) {
    a[0] += blo(r.x); a[1] += bhi(r.x); a[2] += blo(r.y); a[3] += bhi(r.y);
    a[4] += blo(r.z); a[5] += bhi(r.z); a[6] += blo(r.w); a[7] += bhi(r.w);
}

// ---------------- weight swizzle helper (runs inside edge_hist extra blocks) -------
__device__ inline void sw_one(const float* __restrict__ W, ushort* __restrict__ o,
                              int t, int K) {
    const int lane = t & 63, nt = (t >> 6) & 3, ks = t >> 8;
    const int m = lane & 15, quad = lane >> 4;
#pragma unroll
    for (int j = 0; j < 8; ++j) {
        const int kk = ks * 32 + quad * 8 + j;
        const int cc = nt * 16 + m;
        o[t * 8 + j] = f2b(W[kk * 64 + cc]);
    }
}

// ---------------- dual MFMA GEMM: Yl = X@Wl, Yr = X@Wr (bf16 out) ----------------
template<int K, int TPB, bool AF32>
__global__ __launch_bounds__(256) void gemm_mfma(const void* __restrict__ Xv,
                                                 const ushort* __restrict__ Bl,
                                                 const ushort* __restrict__ Br,
                                                 ushort* __restrict__ Yl,
                                                 ushort* __restrict__ Yr) {
    constexpr int KS = K / 32;
    const int lane  = threadIdx.x & 63;
    const int wave  = threadIdx.x >> 6;
    const int nhalf = wave & 1;
    const int rsub  = wave >> 1;
    const int m = lane & 15, quad = lane >> 4;

    v8bf bl[KS][2], br[KS][2];
#pragma unroll
    for (int ks = 0; ks < KS; ++ks)
#pragma unroll
        for (int nt = 0; nt < 2; ++nt) {
            const int nti = nhalf * 2 + nt;
            bl[ks][nt] = *(const v8bf*)(Bl + ((size_t)(ks * 4 + nti) * 64 + lane) * 8);
            br[ks][nt] = *(const v8bf*)(Br + ((size_t)(ks * 4 + nti) * 64 + lane) * 8);
        }

    for (int it = 0; it < TPB; ++it) {
        const int bt = blockIdx.x * TPB + it;
        const int row0 = bt * 32 + rsub * 16;
        if (row0 >= NN) return;
        const v4f z = {0.f, 0.f, 0.f, 0.f};
        v4f accl[2] = {z, z}, accr[2] = {z, z};
#pragma unroll
        for (int ks = 0; ks < KS; ++ks) {
            v8bf a;
            if (AF32) {
                const float* xrow = (const float*)Xv + (size_t)(row0 + m) * K + quad * 8 + ks * 32;
                const float4 a0 = *(const float4*)(xrow);
                const float4 a1 = *(const float4*)(xrow + 4);
                a[0] = (short)f2b(a0.x); a[1] = (short)f2b(a0.y);
                a[2] = (short)f2b(a0.z); a[3] = (short)f2b(a0.w);
                a[4] = (short)f2b(a1.x); a[5] = (short)f2b(a1.y);
                a[6] = (short)f2b(a1.z); a[7] = (short)f2b(a1.w);
            } else {
                const ushort* xrow = (const ushort*)Xv + (size_t)(row0 + m) * K + quad * 8 + ks * 32;
                a = *(const v8bf*)xrow;
            }
#pragma unroll
            for (int nt = 0; nt < 2; ++nt) {
                accl[nt] = __builtin_amdgcn_mfma_f32_16x16x32_bf16(a, bl[ks][nt], accl[nt], 0, 0, 0);
                accr[nt] = __builtin_amdgcn_mfma_f32_16x16x32_bf16(a, br[ks][nt], accr[nt], 0, 0, 0);
            }
        }
#pragma unroll
        for (int nt = 0; nt < 2; ++nt) {
            const int cc = nhalf * 32 + nt * 16 + m;
#pragma unroll
            for (int r = 0; r < 4; ++r) {
                const size_t off = (size_t)(row0 + quad * 4 + r) * 64 + cc;
                Yl[off] = f2b(accl[nt][r]);
                Yr[off] = f2b(accr[nt][r]);
            }
        }
    }
}

// ---------------- pass A1: per-(block,bucket) histogram + fused prep ----------------
__global__ __launch_bounds__(1024) void edge_hist(const int* __restrict__ dst,
                                                  int* __restrict__ hist,
                                                  const float* __restrict__ W1l,
                                                  const float* __restrict__ W1r,
                                                  const float* __restrict__ W2l,
                                                  const float* __restrict__ W2r,
                                                  ushort* __restrict__ w1ls,
                                                  ushort* __restrict__ w1rs,
                                                  ushort* __restrict__ w2ls,
                                                  ushort* __restrict__ w2rs,
                                                  float* __restrict__ gz) {
    if (blockIdx.x >= PBLK) {
        const int t = threadIdx.x;
        if (blockIdx.x == PBLK) {              // 1024 threads: K=128 swizzles
            sw_one(W1l, w1ls, t, FF);
            sw_one(W1r, w1rs, t, FF);
        } else {
            if (t < 512) {                     // K=64 swizzles
                sw_one(W2l, w2ls, t, HH);
                sw_one(W2r, w2rs, t, HH);
            } else {                           // zero gsum (GG*64) + gcnt (GG)
                for (int i = t - 512; i < GG * 64 + GG; i += 512) gz[i] = 0.f;
            }
        }
        return;
    }
    __shared__ int h[NB];
    for (int i = threadIdx.x; i < NB; i += 1024) h[i] = 0;
    __syncthreads();
    const int e0 = blockIdx.x * ECHUNK;
    for (int e = e0 + threadIdx.x; e < e0 + ECHUNK; e += 1024)
        atomicAdd(&h[dst[e] >> 6], 1);
    __syncthreads();
    for (int i = threadIdx.x; i < NB; i += 1024)
        hist[i * PBLK + blockIdx.x] = h[i];   // bucket-major for the scan
}

// ---------------- pass A2: scan (wave-shuffle scan; boff folded into consumers) -----
__global__ __launch_bounds__(256) void scan_block(const int* __restrict__ cnt,
                                                  int* __restrict__ rp,
                                                  int* __restrict__ bsum) {
    __shared__ int ws[4];
    const int tid = threadIdx.x;
    const int lane = tid & 63, wv = tid >> 6;
    const int i = blockIdx.x * 256 + tid;
    const int v = (i < MHIST) ? cnt[i] : 0;
    int inc = v;
#pragma unroll
    for (int off = 1; off < 64; off <<= 1) {
        int t = __shfl_up(inc, off, 64);
        if (lane >= off) inc += t;
    }
    if (lane == 63) ws[wv] = inc;
    __syncthreads();
    int wbase = 0;
#pragma unroll
    for (int w = 0; w < 4; ++w) wbase += (w < wv) ? ws[w] : 0;
    if (i < MHIST) rp[i] = wbase + inc - v;           // exclusive prefix
    if (tid == 255) bsum[blockIdx.x] = wbase + inc;   // block total
}

// scan of NSCAN block sums: 256 threads x 4 elements each (wave-shuffle scan)
__global__ __launch_bounds__(256) void scan_bsums(const int* __restrict__ bsum,
                                                  int* __restrict__ boff) {
    __shared__ int ws[4];
    const int tid = threadIdx.x;
    const int lane = tid & 63, wv = tid >> 6;
    int v[4];
    int tot = 0;
#pragma unroll
    for (int j = 0; j < 4; ++j) {
        const int idx = tid * 4 + j;
        v[j] = (idx < NSCAN) ? bsum[idx] : 0;
        tot += v[j];
    }
    int inc = tot;
#pragma unroll
    for (int off = 1; off < 64; off <<= 1) {
        int t = __shfl_up(inc, off, 64);
        if (lane >= off) inc += t;
    }
    if (lane == 63) ws[wv] = inc;
    __syncthreads();
    int wbase = 0;
#pragma unroll
    for (int w = 0; w < 4; ++w) wbase += (w < wv) ? ws[w] : 0;
    int run = wbase + inc - tot;   // exclusive base for this thread's 4
#pragma unroll
    for (int j = 0; j < 4; ++j) {
        const int idx = tid * 4 + j;
        if (idx < NSCAN) boff[idx] = run;
        run += v[j];
    }
}

// ---------------- pass A3: LDS counting-sort + near-contiguous scatter ----------
__global__ __launch_bounds__(1024) void edge_scatter(const int* __restrict__ src,
                                                     const int* __restrict__ dst,
                                                     const int* __restrict__ hist,
                                                     const int* __restrict__ goffs,
                                                     const int* __restrict__ boff,
                                                     int* __restrict__ pairs) {
    __shared__ int sv[ECHUNK];      // 50000 B: packed (src<<6)|dstLocal, bucket-sorted
    __shared__ int sd[ECHUNK];      // 50000 B: global destination index
    __shared__ int sfill[NB];       //  6252 B: local fill cursor per bucket
    __shared__ int sdelta[NB];      //  6252 B: global_base - local_start per bucket
    __shared__ int wsum[16];
    const int tid = threadIdx.x;
    const int lane = tid & 63, wv = tid >> 6;
    const int p = blockIdx.x;

    int c0 = 0, c1 = 0, g0 = 0, g1 = 0;
    const int i0 = 2 * tid, i1 = 2 * tid + 1;
    if (i0 < NB) {
        const int idx = i0 * PBLK + p;
        c0 = hist[idx];
        g0 = goffs[idx] + boff[idx >> 8];
    }
    if (i1 < NB) {
        const int idx = i1 * PBLK + p;
        c1 = hist[idx];
        g1 = goffs[idx] + boff[idx >> 8];
    }
    const int tv = c0 + c1;
    int inc = tv;
#pragma unroll
    for (int off = 1; off < 64; off <<= 1) {
        int t = __shfl_up(inc, off, 64);
        if (lane >= off) inc += t;
    }
    if (lane == 63) wsum[wv] = inc;
    __syncthreads();
    int wbase = 0;
#pragma unroll
    for (int w = 0; w < 16; ++w) wbase += (w < wv) ? wsum[w] : 0;
    const int excl = wbase + inc - tv;   // local_start for bucket i0
    if (i0 < NB) { sfill[i0] = excl;      sdelta[i0] = g0 - excl; }
    if (i1 < NB) { sfill[i1] = excl + c0; sdelta[i1] = g1 - (excl + c0); }
    __syncthreads();

    const int e0 = p * ECHUNK;
    for (int e = e0 + tid; e < e0 + ECHUNK; e += 1024) {
        const int s = src[e];
        const int d = dst[e];
        const int b = d >> 6;
        const int local = atomicAdd(&sfill[b], 1);
        sv[local] = (s << 6) | (d & (BNODES - 1));
        sd[local] = local + sdelta[b];
    }
    __syncthreads();

    for (int j = tid; j < ECHUNK; j += 1024) {
        pairs[sd[j]] = sv[j];
    }
}

// ---------------- pass B: wave-per-node gather + shfl butterfly + fused epilogue ----
// Phase 4: each wave owns 16 consecutive nodes; per node, 64 lanes = 8 edge-slots
// (grp) x 8 channel-slots (subl). 16 edges in flight (2 per lane), all addresses
// independent; node end: 3-step shfl_xor butterfly over edge-slots (no branches,
// no LDS atomics). Balance = sum of 16 degs per wave (CV ~6%) vs round-2's
// max-of-8-groups (+37%); round-3's per-group run-detection divergence removed.
template<bool POOL>
__global__ __launch_bounds__(256) void spmm_sorted(const int* __restrict__ goffs,
                                                   const int* __restrict__ boff,
                                                   const int* __restrict__ pairs,
                                                   const ushort* __restrict__ Yl,
                                                   const ushort* __restrict__ Yr,
                                                   const float* __restrict__ bias,
                                                   const float* __restrict__ bng,
                                                   const float* __restrict__ bnb,
                                                   const float* __restrict__ bnm,
                                                   const float* __restrict__ bnv,
                                                   ushort* __restrict__ outp,
                                                   const int* __restrict__ batch,
                                                   float* __restrict__ gsum,
                                                   float* __restrict__ gcnt) {
    __shared__ int scol[SCOL_CAP];      // 8 KB: dst-sorted src ids
    __shared__ float accum[BNODES][65]; // 16.6 KB: per-node channel sums
    __shared__ int deg[BNODES];
    __shared__ int loffs[BNODES];       // inclusive scan of deg
    __shared__ int fill[BNODES];
    __shared__ float pbuf[4][64];       // pool partials (POOL only)
    __shared__ float pcnt[4];
    __shared__ int g0s;
    const int tid = threadIdx.x;
    const int b = blockIdx.x;

    if (tid < BNODES) { deg[tid] = 0; fill[tid] = 0; }
    if (POOL) {
        pbuf[tid >> 6][tid & 63] = 0.f;
        if (tid < 4) pcnt[tid] = 0.f;
        if (tid == 0) g0s = batch[b * BNODES];
    }
    __syncthreads();

    const int beg = goffs[b * PBLK] + boff[b >> 1];
    int end = (b == NB - 1) ? NE : goffs[(b + 1) * PBLK] + boff[(b + 1) >> 1];
    if (end - beg > SCOL_CAP) end = beg + SCOL_CAP;

    // phase 1: per-dstLocal degree count (cache pairs in registers for phase 3)
    int pv[8];
    int npv = 0;
    for (int i = beg + tid; i < end; i += 256) {
        const int v = pairs[i];
        pv[npv++] = v;
        atomicAdd(&deg[v & (BNODES - 1)], 1);
    }
    __syncthreads();

    // phase 2: inclusive scan of deg -> loffs (wave 0 shuffle scan)
    if (tid < BNODES) {
        const int v = deg[tid];
        int inc = v;
#pragma unroll
        for (int s = 1; s < 64; s <<= 1) {
            int t = __shfl_up(inc, s, 64);
            if (tid >= s) inc += t;
        }
        loffs[tid] = inc;
    }
    __syncthreads();

    // phase 3: scatter src ids into dst-sorted order (from register cache)
    for (int j = 0; j < npv; ++j) {
        const int v = pv[j];
        const int dl = v & (BNODES - 1);
        const int pos = (loffs[dl] - deg[dl]) + atomicAdd(&fill[dl], 1);
        scol[pos] = v >> 6;
    }
    __syncthreads();

    // phase 4: wave-per-node gather
    const int wv = tid >> 6, lane = tid & 63;
    const int grp = lane >> 3, subl = lane & 7;

    for (int nl = wv * 16; nl < wv * 16 + 16; ++nl) {
        const int dg = deg[nl];
        const int nbeg = loffs[nl] - dg;
        float racc[8] = {0.f, 0.f, 0.f, 0.f, 0.f, 0.f, 0.f, 0.f};
        for (int e = 0; e < dg; e += 16) {
            const int i0 = e + grp;
            const int i1 = e + 8 + grp;
            const bool k0 = i0 < dg, k1 = i1 < dg;
            int s0 = 0, s1 = 0;
            if (k0) s0 = scol[nbeg + i0];
            if (k1) s1 = scol[nbeg + i1];
            uint4 r0, r1;
            if (k0) r0 = *(const uint4*)(Yl + (size_t)s0 * 64 + subl * 8);
            if (k1) r1 = *(const uint4*)(Yl + (size_t)s1 * 64 + subl * 8);
            if (k0) acc8(racc, r0);
            if (k1) acc8(racc, r1);
        }
        // butterfly over the 8 edge-slots (grp dimension): strides 8,16,32
#pragma unroll
        for (int j = 0; j < 8; ++j) {
            racc[j] += __shfl_xor(racc[j], 8, 64);
            racc[j] += __shfl_xor(racc[j], 16, 64);
            racc[j] += __shfl_xor(racc[j], 32, 64);
        }
        if (grp == 0) {
#pragma unroll
            for (int j = 0; j < 8; ++j) accum[nl][subl * 8 + j] = racc[j];
        }
    }
    __syncthreads();

    // phase 5: epilogue — mean + bias + root + BN + ReLU (+ pool or store)
    float biasj[8], scj[8], mj[8], bbj[8];
#pragma unroll
    for (int j = 0; j < 8; ++j) {
        const int ch = subl * 8 + j;
        biasj[j] = bias[ch];
        scj[j] = bng[ch] * rsqrtf(bnv[ch] + BN_EPS);
        mj[j] = bnm[ch];
        bbj[j] = bnb[ch];
    }

    for (int i = 0; i < 2; ++i) {
        const int nl = wv * 16 + i * 8 + grp;
        const int node = b * BNODES + nl;
        if (node >= NN) continue;
        const int dg = deg[nl];
        const float inv = 1.0f / fmaxf((float)dg, 1.0f);
        const uint4 yr = *(const uint4*)(Yr + (size_t)node * 64 + subl * 8);
        float hj[8];
        hj[0] = accum[nl][subl * 8 + 0] * inv + biasj[0] + blo(yr.x);
        hj[1] = accum[nl][subl * 8 + 1] * inv + biasj[1] + bhi(yr.x);
        hj[2] = accum[nl][subl * 8 + 2] * inv + biasj[2] + blo(yr.y);
        hj[3] = accum[nl][subl * 8 + 3] * inv + biasj[3] + bhi(yr.y);
        hj[4] = accum[nl][subl * 8 + 4] * inv + biasj[4] + blo(yr.z);
        hj[5] = accum[nl][subl * 8 + 5] * inv + biasj[5] + bhi(yr.z);
        hj[6] = accum[nl][subl * 8 + 6] * inv + biasj[6] + blo(yr.w);
        hj[7] = accum[nl][subl * 8 + 7] * inv + biasj[7] + bhi(yr.w);
        float o[8];
#pragma unroll
        for (int j = 0; j < 8; ++j)
            o[j] = fmaxf((hj[j] - mj[j]) * scj[j] + bbj[j], 0.0f);
        if (!POOL) {
            unsigned ow[4];
#pragma unroll
            for (int j = 0; j < 4; ++j)
                ow[j] = (unsigned)f2b(o[2 * j]) | ((unsigned)f2b(o[2 * j + 1]) << 16);
            uint4 ov;
            ov.x = ow[0]; ov.y = ow[1]; ov.z = ow[2]; ov.w = ow[3];
            *(uint4*)(outp + (size_t)node * 64 + subl * 8) = ov;
        } else {
            const int g = batch[node];
            const int gi = g - g0s;
            if (gi < 4) {
#pragma unroll
                for (int j = 0; j < 8; ++j) atomicAdd(&pbuf[gi][subl * 8 + j], o[j]);
                if (subl == 0) atomicAdd(&pcnt[gi], 1.0f);
            } else {   // span > 4 graphs in one block: direct (rare/never)
#pragma unroll
                for (int j = 0; j < 8; ++j) atomicAdd(&gsum[g * 64 + subl * 8 + j], o[j]);
                if (subl == 0) atomicAdd(&gcnt[g], 1.0f);
            }
        }
    }
    if (POOL) {
        __syncthreads();
        const int q = tid >> 6, ch = tid & 63;
        const int g = g0s + q;
        if (g < GG) {
            const float v = pbuf[q][ch];
            if (v != 0.f) atomicAdd(&gsum[g * 64 + ch], v);
        }
        if (tid < 4) {
            const int gq = g0s + tid;
            if (gq < GG && pcnt[tid] > 0.f) atomicAdd(&gcnt[gq], pcnt[tid]);
        }
    }
}

// ---------------- classifier head ----------------
__global__ __launch_bounds__(64) void head_kernel(const float* __restrict__ gsum,
                                                  const float* __restrict__ gcnt,
                                                  const float* __restrict__ Wc1,
                                                  const float* __restrict__ bc1,
                                                  const float* __restrict__ g3,
                                                  const float* __restrict__ b3,
                                                  const float* __restrict__ m3,
                                                  const float* __restrict__ v3,
                                                  const float* __restrict__ Wc2,
                                                  const float* __restrict__ bc2,
                                                  float* __restrict__ out) {
    __shared__ float sg[64];
    __shared__ float st[64];
    __shared__ float sl[10];
    __shared__ float sls;
    const int b = blockIdx.x;
    const int c = threadIdx.x;
    sg[c] = gsum[b * 64 + c] / fmaxf(gcnt[b], 1.0f);
    __syncthreads();
    float acc = bc1[c];
#pragma unroll
    for (int k = 0; k < 64; ++k) acc += sg[k] * Wc1[k * 64 + c];
    const float sc = g3[c] * rsqrtf(v3[c] + BN_EPS);
    st[c] = fmaxf((acc - m3[c]) * sc + b3[c], 0.0f);
    __syncthreads();
    if (c < CC) {
        float lg = bc2[c];
#pragma unroll
        for (int k = 0; k < 64; ++k) lg += st[k] * Wc2[k * CC + c];
        sl[c] = lg;
    }
    __syncthreads();
    if (c == 0) {
        float mx = sl[0];
        for (int i = 1; i < CC; ++i) mx = fmaxf(mx, sl[i]);
        float s = 0.f;
        for (int i = 0; i < CC; ++i) s += expf(sl[i] - mx);
        sls = mx + logf(s);
    }
    __syncthreads();
    if (c < CC) out[b * CC + c] = sl[c] - sls;
}

extern "C" void kernel_launch(void* const* d_in, const int* in_sizes, int n_in,
                              void* d_out, int out_size, void* d_ws, size_t ws_size,
                              hipStream_t stream) {
    const float* x    = (const float*)d_in[0];
    const int*   ei   = (const int*)d_in[1];
    const int*   batch= (const int*)d_in[2];
    const float* W1l  = (const float*)d_in[3];
    const float* W1r  = (const float*)d_in[4];
    const float* b1   = (const float*)d_in[5];
    const float* W2l  = (const float*)d_in[6];
    const float* W2r  = (const float*)d_in[7];
    const float* b2   = (const float*)d_in[8];
    const float* bn1g = (const float*)d_in[9];
    const float* bn1b = (const float*)d_in[10];
    const float* bn1m = (const float*)d_in[11];
    const float* bn1v = (const float*)d_in[12];
    const float* bn2g = (const float*)d_in[13];
    const float* bn2b = (const float*)d_in[14];
    const float* bn2m = (const float*)d_in[15];
    const float* bn2v = (const float*)d_in[16];
    const float* bn3g = (const float*)d_in[17];
    const float* bn3b = (const float*)d_in[18];
    const float* bn3m = (const float*)d_in[19];
    const float* bn3v = (const float*)d_in[20];
    const float* Wc1  = (const float*)d_in[21];
    const float* bc1  = (const float*)d_in[22];
    const float* Wc2  = (const float*)d_in[23];
    const float* bc2  = (const float*)d_in[24];
    float* out = (float*)d_out;

    const int* src = ei;
    const int* dst = ei + NE;

    // workspace layout (all blocks 16B-aligned)
    char* p = (char*)d_ws;
    ushort* yl   = (ushort*)p;                 p += (size_t)NN * 64 * 2;        // 12.8 MB
    ushort* yr   = (ushort*)p;                 p += (size_t)NN * 64 * 2;        // 12.8 MB
    ushort* hbuf = (ushort*)p;                 p += (size_t)NN * 64 * 2;        // 12.8 MB
    int*    pairs= (int*)p;                    p += (size_t)NE * 4;             // 6.4 MB
    int*    hist = (int*)p;                    p += (size_t)MHIST * 4;         // 800 KB
    int*    goffs= (int*)p;                    p += (size_t)MHIST * 4;         // 800 KB
    int*    bsum = (int*)p;                    p += 1024 * 4;
    int*    boff = (int*)p;                    p += 1024 * 4;
    ushort* w1ls = (ushort*)p;                 p += (size_t)FF * 64 * 2;
    ushort* w1rs = (ushort*)p;                 p += (size_t)FF * 64 * 2;
    ushort* w2ls = (ushort*)p;                 p += (size_t)HH * 64 * 2;
    ushort* w2rs = (ushort*)p;                 p += (size_t)HH * 64 * 2;
    float* gsum  = (float*)p;                  p += (size_t)GG * 64 * 4;        // gsum+gcnt
    float* gcnt  = gsum + GG * 64;             p += (size_t)GG * 4;             //  contiguous

    // ---- edge counting sort (once, reused by both layers) + fused prep ----
    edge_hist<<<PBLK + 2, 1024, 0, stream>>>(dst, hist, W1l, W1r, W2l, W2r,
                                             w1ls, w1rs, w2ls, w2rs, gsum);
    scan_block<<<NSCAN, 256, 0, stream>>>(hist, goffs, bsum);
    scan_bsums<<<1, 256, 0, stream>>>(bsum, boff);
    edge_scatter<<<PBLK, 1024, 0, stream>>>(src, dst, hist, goffs, boff, pairs);

    // ---- layer 1 ----
    gemm_mfma<FF, 2, true><<<1563, 256, 0, stream>>>((const void*)x, w1ls, w1rs, yl, yr);
    spmm_sorted<false><<<NB, 256, 0, stream>>>(goffs, boff, pairs, yl, yr, b1,
                                               bn1g, bn1b, bn1m, bn1v, hbuf,
                                               batch, gsum, gcnt);

    // ---- layer 2 (pool fused into spmm epilogue; no h write) ----
    gemm_mfma<HH, 2, false><<<1563, 256, 0, stream>>>((const void*)hbuf, w2ls, w2rs, yl, yr);
    spmm_sorted<true><<<NB, 256, 0, stream>>>(goffs, boff, pairs, yl, yr, b2,
                                              bn2g, bn2b, bn2m, bn2v, hbuf,
                                              batch, gsum, gcnt);

    // ---- head ----
    head_kernel<<<GG, 64, 0, stream>>>(gsum, gcnt, Wc1, bc1,
                                       bn3g, bn3b, bn3m, bn3v, Wc2, bc2, out);
}

// Round 6
// 286.018 us; speedup vs baseline: 1.2521x; 1.2233x over previous
//
#include <hip/hip_runtime.h>
#include <hip/hip_bf16.h>
#include <math.h>

#define NN 100000
#define NE 1600000
#define FF 128
#define HH 64
#define CC 10
#define GG 128
#define BN_EPS 1e-5f

// bucketed-edge constants
#define BNODES 64               // nodes per bucket (dst>>6)
#define NB 1563                 // ceil(NN/BNODES)
#define PBLK 128                // partition blocks (counting sort)
#define ECHUNK 12500            // NE / PBLK exactly
#define MHIST (NB * PBLK)       // 200064
#define NSCAN 782               // ceil(MHIST/256)
#define SCOL_CAP 2048           // max edges/bucket in LDS (mean 1024, +32 sigma)

typedef short v8bf __attribute__((ext_vector_type(8)));
typedef float v4f  __attribute__((ext_vector_type(4)));

__device__ inline ushort f2b(float x) {
    __hip_bfloat16 h = __float2bfloat16(x);
    return *reinterpret_cast<ushort*>(&h);
}
__device__ inline float b2f(ushort u) {
    return __uint_as_float(((unsigned)u) << 16);
}
__device__ inline float blo(unsigned u) { return __uint_as_float(u << 16); }
__device__ inline float bhi(unsigned u) { return __uint_as_float(u & 0xffff0000u); }

// accumulate one 128-bit chunk (8 bf16 channels) into a[8]
__device__ inline void acc8(float* a, const uint4 r) {
    a[0] += blo(r.x); a[1] += bhi(r.x); a[2] += blo(r.y); a[3] += bhi(r.y);
    a[4] += blo(r.z); a[5] += bhi(r.z); a[6] += blo(r.w); a[7] += bhi(r.w);
}

// ---------------- weight swizzle helper (runs inside edge_hist extra blocks) -------
__device__ inline void sw_one(const float* __restrict__ W, ushort* __restrict__ o,
                              int t, int K) {
    const int lane = t & 63, nt = (t >> 6) & 3, ks = t >> 8;
    const int m = lane & 15, quad = lane >> 4;
#pragma unroll
    for (int j = 0; j < 8; ++j) {
        const int kk = ks * 32 + quad * 8 + j;
        const int cc = nt * 16 + m;
        o[t * 8 + j] = f2b(W[kk * 64 + cc]);
    }
}

// ---------------- dual MFMA GEMM: Yl = X@Wl, Yr = X@Wr (bf16 out) ----------------
template<int K, int TPB, bool AF32>
__global__ __launch_bounds__(256) void gemm_mfma(const void* __restrict__ Xv,
                                                 const ushort* __restrict__ Bl,
                                                 const ushort* __restrict__ Br,
                                                 ushort* __restrict__ Yl,
                                                 ushort* __restrict__ Yr) {
    constexpr int KS = K / 32;
    const int lane  = threadIdx.x & 63;
    const int wave  = threadIdx.x >> 6;
    const int nhalf = wave & 1;
    const int rsub  = wave >> 1;
    const int m = lane & 15, quad = lane >> 4;

    v8bf bl[KS][2], br[KS][2];
#pragma unroll
    for (int ks = 0; ks < KS; ++ks)
#pragma unroll
        for (int nt = 0; nt < 2; ++nt) {
            const int nti = nhalf * 2 + nt;
            bl[ks][nt] = *(const v8bf*)(Bl + ((size_t)(ks * 4 + nti) * 64 + lane) * 8);
            br[ks][nt] = *(const v8bf*)(Br + ((size_t)(ks * 4 + nti) * 64 + lane) * 8);
        }

    for (int it = 0; it < TPB; ++it) {
        const int bt = blockIdx.x * TPB + it;
        const int row0 = bt * 32 + rsub * 16;
        if (row0 >= NN) return;
        const v4f z = {0.f, 0.f, 0.f, 0.f};
        v4f accl[2] = {z, z}, accr[2] = {z, z};
#pragma unroll
        for (int ks = 0; ks < KS; ++ks) {
            v8bf a;
            if (AF32) {
                const float* xrow = (const float*)Xv + (size_t)(row0 + m) * K + quad * 8 + ks * 32;
                const float4 a0 = *(const float4*)(xrow);
                const float4 a1 = *(const float4*)(xrow + 4);
                a[0] = (short)f2b(a0.x); a[1] = (short)f2b(a0.y);
                a[2] = (short)f2b(a0.z); a[3] = (short)f2b(a0.w);
                a[4] = (short)f2b(a1.x); a[5] = (short)f2b(a1.y);
                a[6] = (short)f2b(a1.z); a[7] = (short)f2b(a1.w);
            } else {
                const ushort* xrow = (const ushort*)Xv + (size_t)(row0 + m) * K + quad * 8 + ks * 32;
                a = *(const v8bf*)xrow;
            }
#pragma unroll
            for (int nt = 0; nt < 2; ++nt) {
                accl[nt] = __builtin_amdgcn_mfma_f32_16x16x32_bf16(a, bl[ks][nt], accl[nt], 0, 0, 0);
                accr[nt] = __builtin_amdgcn_mfma_f32_16x16x32_bf16(a, br[ks][nt], accr[nt], 0, 0, 0);
            }
        }
#pragma unroll
        for (int nt = 0; nt < 2; ++nt) {
            const int cc = nhalf * 32 + nt * 16 + m;
#pragma unroll
            for (int r = 0; r < 4; ++r) {
                const size_t off = (size_t)(row0 + quad * 4 + r) * 64 + cc;
                Yl[off] = f2b(accl[nt][r]);
                Yr[off] = f2b(accr[nt][r]);
            }
        }
    }
}

// ---------------- pass A1: per-(block,bucket) histogram + fused prep ----------------
__global__ __launch_bounds__(1024) void edge_hist(const int* __restrict__ dst,
                                                  int* __restrict__ hist,
                                                  const float* __restrict__ W1l,
                                                  const float* __restrict__ W1r,
                                                  const float* __restrict__ W2l,
                                                  const float* __restrict__ W2r,
                                                  ushort* __restrict__ w1ls,
                                                  ushort* __restrict__ w1rs,
                                                  ushort* __restrict__ w2ls,
                                                  ushort* __restrict__ w2rs,
                                                  float* __restrict__ gz) {
    if (blockIdx.x >= PBLK) {
        const int t = threadIdx.x;
        if (blockIdx.x == PBLK) {              // 1024 threads: K=128 swizzles
            sw_one(W1l, w1ls, t, FF);
            sw_one(W1r, w1rs, t, FF);
        } else {
            if (t < 512) {                     // K=64 swizzles
                sw_one(W2l, w2ls, t, HH);
                sw_one(W2r, w2rs, t, HH);
            } else {                           // zero gsum (GG*64) + gcnt (GG)
                for (int i = t - 512; i < GG * 64 + GG; i += 512) gz[i] = 0.f;
            }
        }
        return;
    }
    __shared__ int h[NB];
    for (int i = threadIdx.x; i < NB; i += 1024) h[i] = 0;
    __syncthreads();
    const int e0 = blockIdx.x * ECHUNK;
    for (int e = e0 + threadIdx.x; e < e0 + ECHUNK; e += 1024)
        atomicAdd(&h[dst[e] >> 6], 1);
    __syncthreads();
    for (int i = threadIdx.x; i < NB; i += 1024)
        hist[i * PBLK + blockIdx.x] = h[i];   // bucket-major for the scan
}

// ---------------- pass A2: scan (wave-shuffle scan; boff folded into consumers) -----
__global__ __launch_bounds__(256) void scan_block(const int* __restrict__ cnt,
                                                  int* __restrict__ rp,
                                                  int* __restrict__ bsum) {
    __shared__ int ws[4];
    const int tid = threadIdx.x;
    const int lane = tid & 63, wv = tid >> 6;
    const int i = blockIdx.x * 256 + tid;
    const int v = (i < MHIST) ? cnt[i] : 0;
    int inc = v;
#pragma unroll
    for (int off = 1; off < 64; off <<= 1) {
        int t = __shfl_up(inc, off, 64);
        if (lane >= off) inc += t;
    }
    if (lane == 63) ws[wv] = inc;
    __syncthreads();
    int wbase = 0;
#pragma unroll
    for (int w = 0; w < 4; ++w) wbase += (w < wv) ? ws[w] : 0;
    if (i < MHIST) rp[i] = wbase + inc - v;           // exclusive prefix
    if (tid == 255) bsum[blockIdx.x] = wbase + inc;   // block total
}

// scan of NSCAN block sums: 256 threads x 4 elements each (wave-shuffle scan)
__global__ __launch_bounds__(256) void scan_bsums(const int* __restrict__ bsum,
                                                  int* __restrict__ boff) {
    __shared__ int ws[4];
    const int tid = threadIdx.x;
    const int lane = tid & 63, wv = tid >> 6;
    int v[4];
    int tot = 0;
#pragma unroll
    for (int j = 0; j < 4; ++j) {
        const int idx = tid * 4 + j;
        v[j] = (idx < NSCAN) ? bsum[idx] : 0;
        tot += v[j];
    }
    int inc = tot;
#pragma unroll
    for (int off = 1; off < 64; off <<= 1) {
        int t = __shfl_up(inc, off, 64);
        if (lane >= off) inc += t;
    }
    if (lane == 63) ws[wv] = inc;
    __syncthreads();
    int wbase = 0;
#pragma unroll
    for (int w = 0; w < 4; ++w) wbase += (w < wv) ? ws[w] : 0;
    int run = wbase + inc - tot;   // exclusive base for this thread's 4
#pragma unroll
    for (int j = 0; j < 4; ++j) {
        const int idx = tid * 4 + j;
        if (idx < NSCAN) boff[idx] = run;
        run += v[j];
    }
}

// ---------------- pass A3: LDS counting-sort + near-contiguous scatter ----------
__global__ __launch_bounds__(1024) void edge_scatter(const int* __restrict__ src,
                                                     const int* __restrict__ dst,
                                                     const int* __restrict__ hist,
                                                     const int* __restrict__ goffs,
                                                     const int* __restrict__ boff,
                                                     int* __restrict__ pairs) {
    __shared__ int sv[ECHUNK];      // 50000 B: packed (src<<6)|dstLocal, bucket-sorted
    __shared__ int sd[ECHUNK];      // 50000 B: global destination index
    __shared__ int sfill[NB];       //  6252 B: local fill cursor per bucket
    __shared__ int sdelta[NB];      //  6252 B: global_base - local_start per bucket
    __shared__ int wsum[16];
    const int tid = threadIdx.x;
    const int lane = tid & 63, wv = tid >> 6;
    const int p = blockIdx.x;

    int c0 = 0, c1 = 0, g0 = 0, g1 = 0;
    const int i0 = 2 * tid, i1 = 2 * tid + 1;
    if (i0 < NB) {
        const int idx = i0 * PBLK + p;
        c0 = hist[idx];
        g0 = goffs[idx] + boff[idx >> 8];
    }
    if (i1 < NB) {
        const int idx = i1 * PBLK + p;
        c1 = hist[idx];
        g1 = goffs[idx] + boff[idx >> 8];
    }
    const int tv = c0 + c1;
    int inc = tv;
#pragma unroll
    for (int off = 1; off < 64; off <<= 1) {
        int t = __shfl_up(inc, off, 64);
        if (lane >= off) inc += t;
    }
    if (lane == 63) wsum[wv] = inc;
    __syncthreads();
    int wbase = 0;
#pragma unroll
    for (int w = 0; w < 16; ++w) wbase += (w < wv) ? wsum[w] : 0;
    const int excl = wbase + inc - tv;   // local_start for bucket i0
    if (i0 < NB) { sfill[i0] = excl;      sdelta[i0] = g0 - excl; }
    if (i1 < NB) { sfill[i1] = excl + c0; sdelta[i1] = g1 - (excl + c0); }
    __syncthreads();

    const int e0 = p * ECHUNK;
    for (int e = e0 + tid; e < e0 + ECHUNK; e += 1024) {
        const int s = src[e];
        const int d = dst[e];
        const int b = d >> 6;
        const int local = atomicAdd(&sfill[b], 1);
        sv[local] = (s << 6) | (d & (BNODES - 1));
        sd[local] = local + sdelta[b];
    }
    __syncthreads();

    for (int j = tid; j < ECHUNK; j += 1024) {
        pairs[sd[j]] = sv[j];
    }
}

// ---------------- pass B: group-per-node register gather + fused epilogue ----------
// 512 threads = 64 groups of 8 lanes; group g owns node g (one node per group).
// Inner loop identical to the proven round-2 body: serial edge walk, 4 uint4 loads
// in flight, register accumulate, zero cross-lane work. 8 waves/block doubles
// resident waves vs 256-thread version -> hides LLC gather latency via TLP.
template<bool POOL>
__global__ __launch_bounds__(512) void spmm_sorted(const int* __restrict__ goffs,
                                                   const int* __restrict__ boff,
                                                   const int* __restrict__ pairs,
                                                   const ushort* __restrict__ Yl,
                                                   const ushort* __restrict__ Yr,
                                                   const float* __restrict__ bias,
                                                   const float* __restrict__ bng,
                                                   const float* __restrict__ bnb,
                                                   const float* __restrict__ bnm,
                                                   const float* __restrict__ bnv,
                                                   ushort* __restrict__ outp,
                                                   const int* __restrict__ batch,
                                                   float* __restrict__ gsum,
                                                   float* __restrict__ gcnt) {
    __shared__ int scol[SCOL_CAP];      // 8 KB: dst-sorted src ids
    __shared__ int deg[BNODES];
    __shared__ int loffs[BNODES];       // inclusive scan of deg
    __shared__ int fill[BNODES];
    __shared__ float pbuf[4][64];       // pool partials (POOL only)
    __shared__ float pcnt[4];
    __shared__ int g0s;
    const int tid = threadIdx.x;
    const int b = blockIdx.x;

    if (tid < BNODES) { deg[tid] = 0; fill[tid] = 0; }
    if (POOL) {
        if (tid < 256) pbuf[tid >> 6][tid & 63] = 0.f;
        if (tid < 4) pcnt[tid] = 0.f;
        if (tid == 0) g0s = batch[b * BNODES];
    }
    __syncthreads();

    const int beg = goffs[b * PBLK] + boff[b >> 1];
    int end = (b == NB - 1) ? NE : goffs[(b + 1) * PBLK] + boff[(b + 1) >> 1];
    if (end - beg > SCOL_CAP) end = beg + SCOL_CAP;

    // phase 1: per-dstLocal degree count (cache pairs in registers for phase 3)
    int pv[4];
    int npv = 0;
    for (int i = beg + tid; i < end; i += 512) {
        const int v = pairs[i];
        pv[npv++] = v;
        atomicAdd(&deg[v & (BNODES - 1)], 1);
    }
    __syncthreads();

    // phase 2: inclusive scan of deg -> loffs (wave 0 shuffle scan)
    if (tid < BNODES) {
        const int v = deg[tid];
        int inc = v;
#pragma unroll
        for (int s = 1; s < 64; s <<= 1) {
            int t = __shfl_up(inc, s, 64);
            if (tid >= s) inc += t;
        }
        loffs[tid] = inc;
    }
    __syncthreads();

    // phase 3: scatter src ids into dst-sorted order (from register cache)
    for (int j = 0; j < npv; ++j) {
        const int v = pv[j];
        const int dl = v & (BNODES - 1);
        const int pos = (loffs[dl] - deg[dl]) + atomicAdd(&fill[dl], 1);
        scol[pos] = v >> 6;
    }
    __syncthreads();

    // phase 4: gather + mean + bias + root + BN + ReLU (+ pool or store)
    // group gid (8 lanes) owns node gid; subl = channel octet
    const int gid = tid >> 3, subl = tid & 7;
    const int nl = gid;
    const int node = b * BNODES + nl;
    if (node < NN) {
        const int dg = deg[nl];
        const int nbeg = loffs[nl] - dg;
        const int nend = nbeg + dg;
        float a[8] = {0.f, 0.f, 0.f, 0.f, 0.f, 0.f, 0.f, 0.f};
        float c[8] = {0.f, 0.f, 0.f, 0.f, 0.f, 0.f, 0.f, 0.f};
        int e = nbeg;
        // 4 loads in flight (proven round-2 body)
        for (; e + 3 < nend; e += 4) {
            const int s0 = scol[e], s1 = scol[e + 1], s2 = scol[e + 2], s3 = scol[e + 3];
            const uint4 r0 = *(const uint4*)(Yl + (size_t)s0 * 64 + subl * 8);
            const uint4 r1 = *(const uint4*)(Yl + (size_t)s1 * 64 + subl * 8);
            const uint4 r2 = *(const uint4*)(Yl + (size_t)s2 * 64 + subl * 8);
            const uint4 r3 = *(const uint4*)(Yl + (size_t)s3 * 64 + subl * 8);
            acc8(a, r0); acc8(c, r1); acc8(a, r2); acc8(c, r3);
        }
        if (e + 1 < nend) {
            const int s0 = scol[e], s1 = scol[e + 1];
            const uint4 r0 = *(const uint4*)(Yl + (size_t)s0 * 64 + subl * 8);
            const uint4 r1 = *(const uint4*)(Yl + (size_t)s1 * 64 + subl * 8);
            acc8(a, r0); acc8(c, r1);
            e += 2;
        }
        if (e < nend) {
            const int s0 = scol[e];
            const uint4 r0 = *(const uint4*)(Yl + (size_t)s0 * 64 + subl * 8);
            acc8(a, r0);
        }
        float biasj[8], scj[8], mj[8], bbj[8];
#pragma unroll
        for (int j = 0; j < 8; ++j) {
            const int ch = subl * 8 + j;
            biasj[j] = bias[ch];
            scj[j] = bng[ch] * rsqrtf(bnv[ch] + BN_EPS);
            mj[j] = bnm[ch];
            bbj[j] = bnb[ch];
        }
        const float inv = 1.0f / fmaxf((float)dg, 1.0f);
        const uint4 yr = *(const uint4*)(Yr + (size_t)node * 64 + subl * 8);
        float hj[8];
        hj[0] = (a[0] + c[0]) * inv + biasj[0] + blo(yr.x);
        hj[1] = (a[1] + c[1]) * inv + biasj[1] + bhi(yr.x);
        hj[2] = (a[2] + c[2]) * inv + biasj[2] + blo(yr.y);
        hj[3] = (a[3] + c[3]) * inv + biasj[3] + bhi(yr.y);
        hj[4] = (a[4] + c[4]) * inv + biasj[4] + blo(yr.z);
        hj[5] = (a[5] + c[5]) * inv + biasj[5] + bhi(yr.z);
        hj[6] = (a[6] + c[6]) * inv + biasj[6] + blo(yr.w);
        hj[7] = (a[7] + c[7]) * inv + biasj[7] + bhi(yr.w);
        float o[8];
#pragma unroll
        for (int j = 0; j < 8; ++j)
            o[j] = fmaxf((hj[j] - mj[j]) * scj[j] + bbj[j], 0.0f);
        if (!POOL) {
            unsigned ow[4];
#pragma unroll
            for (int j = 0; j < 4; ++j)
                ow[j] = (unsigned)f2b(o[2 * j]) | ((unsigned)f2b(o[2 * j + 1]) << 16);
            uint4 ov;
            ov.x = ow[0]; ov.y = ow[1]; ov.z = ow[2]; ov.w = ow[3];
            *(uint4*)(outp + (size_t)node * 64 + subl * 8) = ov;
        } else {
            const int g = batch[node];
            const int gi = g - g0s;
            if (gi < 4) {
#pragma unroll
                for (int j = 0; j < 8; ++j) atomicAdd(&pbuf[gi][subl * 8 + j], o[j]);
                if (subl == 0) atomicAdd(&pcnt[gi], 1.0f);
            } else {   // span > 4 graphs in one block: direct (rare/never)
#pragma unroll
                for (int j = 0; j < 8; ++j) atomicAdd(&gsum[g * 64 + subl * 8 + j], o[j]);
                if (subl == 0) atomicAdd(&gcnt[g], 1.0f);
            }
        }
    }
    if (POOL) {
        __syncthreads();
        if (tid < 256) {
            const int q = tid >> 6, ch = tid & 63;
            const int g = g0s + q;
            if (g < GG) {
                const float v = pbuf[q][ch];
                if (v != 0.f) atomicAdd(&gsum[g * 64 + ch], v);
            }
        }
        if (tid < 4) {
            const int gq = g0s + tid;
            if (gq < GG && pcnt[tid] > 0.f) atomicAdd(&gcnt[gq], pcnt[tid]);
        }
    }
}

// ---------------- classifier head ----------------
__global__ __launch_bounds__(64) void head_kernel(const float* __restrict__ gsum,
                                                  const float* __restrict__ gcnt,
                                                  const float* __restrict__ Wc1,
                                                  const float* __restrict__ bc1,
                                                  const float* __restrict__ g3,
                                                  const float* __restrict__ b3,
                                                  const float* __restrict__ m3,
                                                  const float* __restrict__ v3,
                                                  const float* __restrict__ Wc2,
                                                  const float* __restrict__ bc2,
                                                  float* __restrict__ out) {
    __shared__ float sg[64];
    __shared__ float st[64];
    __shared__ float sl[10];
    __shared__ float sls;
    const int b = blockIdx.x;
    const int c = threadIdx.x;
    sg[c] = gsum[b * 64 + c] / fmaxf(gcnt[b], 1.0f);
    __syncthreads();
    float acc = bc1[c];
#pragma unroll
    for (int k = 0; k < 64; ++k) acc += sg[k] * Wc1[k * 64 + c];
    const float sc = g3[c] * rsqrtf(v3[c] + BN_EPS);
    st[c] = fmaxf((acc - m3[c]) * sc + b3[c], 0.0f);
    __syncthreads();
    if (c < CC) {
        float lg = bc2[c];
#pragma unroll
        for (int k = 0; k < 64; ++k) lg += st[k] * Wc2[k * CC + c];
        sl[c] = lg;
    }
    __syncthreads();
    if (c == 0) {
        float mx = sl[0];
        for (int i = 1; i < CC; ++i) mx = fmaxf(mx, sl[i]);
        float s = 0.f;
        for (int i = 0; i < CC; ++i) s += expf(sl[i] - mx);
        sls = mx + logf(s);
    }
    __syncthreads();
    if (c < CC) out[b * CC + c] = sl[c] - sls;
}

extern "C" void kernel_launch(void* const* d_in, const int* in_sizes, int n_in,
                              void* d_out, int out_size, void* d_ws, size_t ws_size,
                              hipStream_t stream) {
    const float* x    = (const float*)d_in[0];
    const int*   ei   = (const int*)d_in[1];
    const int*   batch= (const int*)d_in[2];
    const float* W1l  = (const float*)d_in[3];
    const float* W1r  = (const float*)d_in[4];
    const float* b1   = (const float*)d_in[5];
    const float* W2l  = (const float*)d_in[6];
    const float* W2r  = (const float*)d_in[7];
    const float* b2   = (const float*)d_in[8];
    const float* bn1g = (const float*)d_in[9];
    const float* bn1b = (const float*)d_in[10];
    const float* bn1m = (const float*)d_in[11];
    const float* bn1v = (const float*)d_in[12];
    const float* bn2g = (const float*)d_in[13];
    const float* bn2b = (const float*)d_in[14];
    const float* bn2m = (const float*)d_in[15];
    const float* bn2v = (const float*)d_in[16];
    const float* bn3g = (const float*)d_in[17];
    const float* bn3b = (const float*)d_in[18];
    const float* bn3m = (const float*)d_in[19];
    const float* bn3v = (const float*)d_in[20];
    const float* Wc1  = (const float*)d_in[21];
    const float* bc1  = (const float*)d_in[22];
    const float* Wc2  = (const float*)d_in[23];
    const float* bc2  = (const float*)d_in[24];
    float* out = (float*)d_out;

    const int* src = ei;
    const int* dst = ei + NE;

    // workspace layout (all blocks 16B-aligned)
    char* p = (char*)d_ws;
    ushort* yl   = (ushort*)p;                 p += (size_t)NN * 64 * 2;        // 12.8 MB
    ushort* yr   = (ushort*)p;                 p += (size_t)NN * 64 * 2;        // 12.8 MB
    ushort* hbuf = (ushort*)p;                 p += (size_t)NN * 64 * 2;        // 12.8 MB
    int*    pairs= (int*)p;                    p += (size_t)NE * 4;             // 6.4 MB
    int*    hist = (int*)p;                    p += (size_t)MHIST * 4;         // 800 KB
    int*    goffs= (int*)p;                    p += (size_t)MHIST * 4;         // 800 KB
    int*    bsum = (int*)p;                    p += 1024 * 4;
    int*    boff = (int*)p;                    p += 1024 * 4;
    ushort* w1ls = (ushort*)p;                 p += (size_t)FF * 64 * 2;
    ushort* w1rs = (ushort*)p;                 p += (size_t)FF * 64 * 2;
    ushort* w2ls = (ushort*)p;                 p += (size_t)HH * 64 * 2;
    ushort* w2rs = (ushort*)p;                 p += (size_t)HH * 64 * 2;
    float* gsum  = (float*)p;                  p += (size_t)GG * 64 * 4;        // gsum+gcnt
    float* gcnt  = gsum + GG * 64;             p += (size_t)GG * 4;             //  contiguous

    // ---- edge counting sort (once, reused by both layers) + fused prep ----
    edge_hist<<<PBLK + 2, 1024, 0, stream>>>(dst, hist, W1l, W1r, W2l, W2r,
                                             w1ls, w1rs, w2ls, w2rs, gsum);
    scan_block<<<NSCAN, 256, 0, stream>>>(hist, goffs, bsum);
    scan_bsums<<<1, 256, 0, stream>>>(bsum, boff);
    edge_scatter<<<PBLK, 1024, 0, stream>>>(src, dst, hist, goffs, boff, pairs);

    // ---- layer 1 ----
    gemm_mfma<FF, 2, true><<<1563, 256, 0, stream>>>((const void*)x, w1ls, w1rs, yl, yr);
    spmm_sorted<false><<<NB, 512, 0, stream>>>(goffs, boff, pairs, yl, yr, b1,
                                               bn1g, bn1b, bn1m, bn1v, hbuf,
                                               batch, gsum, gcnt);

    // ---- layer 2 (pool fused into spmm epilogue; no h write) ----
    gemm_mfma<HH, 2, false><<<1563, 256, 0, stream>>>((const void*)hbuf, w2ls, w2rs, yl, yr);
    spmm_sorted<true><<<NB, 512, 0, stream>>>(goffs, boff, pairs, yl, yr, b2,
                                              bn2g, bn2b, bn2m, bn2v, hbuf,
                                              batch, gsum, gcnt);

    // ---- head ----
    head_kernel<<<GG, 64, 0, stream>>>(gsum, gcnt, Wc1, bc1,
                                       bn3g, bn3b, bn3m, bn3v, Wc2, bc2, out);
}